// Round 5
// baseline (671.208 us; speedup 1.0000x reference)
//
#include <hip/hip_runtime.h>
#include <stdint.h>

// ---------------------------------------------------------------------------
// Attention block: x@wqkv (fused) -> RoPE -> causal flash attention -> @wo
// B=1 S=2048 D=4096 H=32 KVH=8 HD=128. bf16 MFMA, fp32 accumulate.
// GQA (reference _repeat_kv, rep OUTER): head h -> kv head h%8.
// ---------------------------------------------------------------------------

using bf16x8 = __attribute__((ext_vector_type(8))) short;
using f32x4  = __attribute__((ext_vector_type(4))) float;
using s16x4  = __attribute__((ext_vector_type(4))) short;

__device__ __forceinline__ short f2bf(float f) {
    union { float f; unsigned u; } v; v.f = f;
    unsigned r = v.u + 0x7fffu + ((v.u >> 16) & 1u);   // RNE
    return (short)(r >> 16);
}
__device__ __forceinline__ float bf2f(short s) {
    union { unsigned u; float f; } v; v.u = ((unsigned)(unsigned short)s) << 16;
    return v.f;
}

// async global->LDS DMA, 16B/lane; LDS dest = wave-uniform base + lane*16
#define GLL16(gp, lp)                                                          \
    __builtin_amdgcn_global_load_lds(                                          \
        (const __attribute__((address_space(1))) void*)(gp),                   \
        (__attribute__((address_space(3))) void*)(lp), 16, 0, 0)

// --------------------------- x fp32 -> bf16 --------------------------------
__global__ __launch_bounds__(256) void cvt_f32_bf16(const float* __restrict__ x,
                                                    short* __restrict__ y, int n) {
    int i = (blockIdx.x * 256 + threadIdx.x) * 4;
    if (i >= n) return;
    f32x4 v = *(const f32x4*)(x + i);
    s16x4 o;
    o.x = f2bf(v.x); o.y = f2bf(v.y); o.z = f2bf(v.z); o.w = f2bf(v.w);
    *(s16x4*)(y + i) = o;
}

// ------------- W[K][N] fp32 -> WT[N][K] bf16, 64k x 32n tiles --------------
// writes packed 2xbf16 (4B/lane -> 128B segments)
__global__ __launch_bounds__(256) void transpose_f32_bf16(const float* __restrict__ W,
                                                          short* __restrict__ WT,
                                                          int K, int N) {
    __shared__ float t[64][33];
    int n0 = blockIdx.x * 32, k0 = blockIdx.y * 64;
    int tx = threadIdx.x, ty = threadIdx.y;   // (32,8)
#pragma unroll
    for (int i = 0; i < 64; i += 8)
        t[ty + i][tx] = W[(size_t)(k0 + ty + i) * N + n0 + tx];
    __syncthreads();
#pragma unroll
    for (int i = 0; i < 32; i += 8) {
        int n = ty + i;
        unsigned lo = (unsigned short)f2bf(t[2 * tx][n]);
        unsigned hi = (unsigned short)f2bf(t[2 * tx + 1][n]);
        *(unsigned*)&WT[(size_t)(n0 + n) * K + k0 + 2 * tx] = lo | (hi << 16);
    }
}

// ---------------- A[R][C] bf16 (lda) -> AT[C][R] bf16 ----------------------
__global__ __launch_bounds__(256) void transpose_bf16(const short* __restrict__ A,
                                                      short* __restrict__ AT,
                                                      int R, int C, int lda) {
    __shared__ short t[32][33];
    int c0 = blockIdx.x * 32, r0 = blockIdx.y * 32;
    int tx = threadIdx.x, ty = threadIdx.y;
#pragma unroll
    for (int i = 0; i < 32; i += 8)
        t[ty + i][tx] = A[(size_t)(r0 + ty + i) * lda + c0 + tx];
    __syncthreads();
#pragma unroll
    for (int i = 0; i < 32; i += 8)
        AT[(size_t)(c0 + ty + i) * R + r0 + tx] = t[tx][ty + i];
}

// --------------------------- bf16 MFMA GEMM --------------------------------
// C[M][N] = A[M][K] * BT[N][K]^T.  128x128 tile, BK=64 as TWO 32-k panels
// (panel-linear LDS keeps GLL16 legal AND keeps 64B-row frag reads),
// 4 waves of 64x64, global_load_lds width-16 staging.
__global__ __launch_bounds__(256) void gemm_bf16(const short* __restrict__ A,
                                                 const short* __restrict__ BT,
                                                 float* __restrict__ Cf,
                                                 short* __restrict__ Cb,
                                                 int M, int N, int K) {
    __shared__ short As[2 * 128 * 32];
    __shared__ short Bs[2 * 128 * 32];
    const int tid  = threadIdx.x;
    const int wave = tid >> 6, lane = tid & 63;
    const int lrow = lane & 15, quad = lane >> 4, lk8 = quad * 8;
    const int bm = blockIdx.y * 128, bn = blockIdx.x * 128;
    const int wm = (wave >> 1) * 64, wn = (wave & 1) * 64;

    f32x4 acc[4][4];
#pragma unroll
    for (int i = 0; i < 4; i++)
#pragma unroll
        for (int j = 0; j < 4; j++) acc[i][j] = (f32x4){0.f, 0.f, 0.f, 0.f};

    for (int k0 = 0; k0 < K; k0 += 64) {
        __syncthreads();
#pragma unroll
        for (int s = 0; s < 4; s++) {
            int idx = tid * 8 + s * 2048;            // 0..8191
            int panel = idx >> 12, rem = idx & 4095;
            int row = rem >> 5, col = (panel << 5) + (rem & 31);
            GLL16(A  + (size_t)(bm + row) * K + k0 + col, &As[idx]);
            GLL16(BT + (size_t)(bn + row) * K + k0 + col, &Bs[idx]);
        }
        __syncthreads();
#pragma unroll
        for (int p = 0; p < 2; p++) {
            bf16x8 af[4], bfr[4];
#pragma unroll
            for (int i = 0; i < 4; i++)
                af[i]  = *(const bf16x8*)&As[p * 4096 + (wm + i * 16 + lrow) * 32 + lk8];
#pragma unroll
            for (int j = 0; j < 4; j++)
                bfr[j] = *(const bf16x8*)&Bs[p * 4096 + (wn + j * 16 + lrow) * 32 + lk8];
#pragma unroll
            for (int i = 0; i < 4; i++)
#pragma unroll
                for (int j = 0; j < 4; j++)
                    acc[i][j] = __builtin_amdgcn_mfma_f32_16x16x32_bf16(af[i], bfr[j], acc[i][j], 0, 0, 0);
        }
    }

    // C/D layout: col = lane&15, row = quad*4 + reg (m89-verified)
#pragma unroll
    for (int i = 0; i < 4; i++)
#pragma unroll
        for (int j = 0; j < 4; j++)
#pragma unroll
            for (int r = 0; r < 4; r++) {
                int m = bm + wm + i * 16 + quad * 4 + r;
                int n = bn + wn + j * 16 + lrow;
                float v = acc[i][j][r];
                if (Cf) Cf[(size_t)m * N + n] = v;
                else    Cb[(size_t)m * N + n] = f2bf(v);
            }
}

// ----------------------------- RoPE in place -------------------------------
// qkv rows [2048][6144]: cols 0..4095 Q, 4096..5119 K, rest V (untouched)
__global__ __launch_bounds__(256) void rope_kernel(short* __restrict__ qkv,
                                                   const float* __restrict__ fc,
                                                   const float* __restrict__ fs) {
    int s = blockIdx.x, t = threadIdx.x;
#pragma unroll
    for (int p = t; p < 2048; p += 256) {         // Q: 2048 pairs
        int i = p & 63;
        float c = fc[s * 64 + i], sn = fs[s * 64 + i];
        size_t base = (size_t)s * 6144 + 2 * p;
        float e = bf2f(qkv[base]), o = bf2f(qkv[base + 1]);
        qkv[base]     = f2bf(e * c - o * sn);
        qkv[base + 1] = f2bf(o * c + e * sn);
    }
#pragma unroll
    for (int p = t; p < 512; p += 256) {          // K: 512 pairs
        int i = p & 63;
        float c = fc[s * 64 + i], sn = fs[s * 64 + i];
        size_t base = (size_t)s * 6144 + 4096 + 2 * p;
        float e = bf2f(qkv[base]), o = bf2f(qkv[base + 1]);
        qkv[base]     = f2bf(e * c - o * sn);
        qkv[base + 1] = f2bf(o * c + e * sn);
    }
}

// -------------------------- flash attention v3 -----------------------------
// grid (64 qblocks of 32 rows, 8 kv heads); 4 waves; wave w -> head w*8+kvh.
// 64-key tiles (2 barriers per 64 keys), fixed-max softmax, deferred l.
#define KSLD 136    // K tile row stride (shorts): 2-way banks on frag reads
#define VSLD 68     // V^T tile row stride
#define PSLD 68     // P scratch row stride
__global__ __launch_bounds__(256) void attn_kernel(const short* __restrict__ QKV,
                                                   const short* __restrict__ VT,
                                                   short* __restrict__ AO) {
    const int qb = 63 - blockIdx.x;               // LPT: big blocks first
    const int kvh = blockIdx.y;
    const int wave = threadIdx.x >> 6, lane = threadIdx.x & 63;
    const int lrow = lane & 15, quad = lane >> 4, lk8 = quad * 8;
    const int h = wave * 8 + kvh;                 // rep-outer GQA mapping
    const int q0 = qb * 32;

    __shared__ short Ks[64 * KSLD];               // [key][d]
    __shared__ short Vs[128 * VSLD];              // [d][key]
    __shared__ short Pw[4][2][16 * PSLD];         // per-wave P transit

    bf16x8 aq[2][4];
#pragma unroll
    for (int rs = 0; rs < 2; rs++) {
        const short* qrow = QKV + (size_t)(q0 + rs * 16 + lrow) * 6144 + h * 128;
#pragma unroll
        for (int f = 0; f < 4; f++) aq[rs][f] = *(const bf16x8*)(qrow + f * 32 + lk8);
    }

    f32x4 o_acc[2][8];
#pragma unroll
    for (int rs = 0; rs < 2; rs++)
#pragma unroll
        for (int d = 0; d < 8; d++) o_acc[rs][d] = (f32x4){0.f, 0.f, 0.f, 0.f};
    float l_part[2][4];
#pragma unroll
    for (int rs = 0; rs < 2; rs++)
#pragma unroll
        for (int r = 0; r < 4; r++) l_part[rs][r] = 0.f;

    const int nkt = (qb + 2) >> 1;                // ceil((q0+32)/64)
    const float sc = 0.08838834764831845f;        // 1/sqrt(128)
    const short* Kbase = QKV + 4096;              // K cols in fused buffer

    for (int kt = 0; kt < nkt; kt++) {
        __syncthreads();
        // stage K tile [64][128] and V^T tile [128][64]; 8192 elts each
#pragma unroll
        for (int c = 0; c < 4; c++) {
            int idx = (threadIdx.x + c * 256) * 8;          // 0..8191
            int key = idx >> 7, d = idx & 127;
            *(bf16x8*)&Ks[key * KSLD + d] =
                *(const bf16x8*)(Kbase + (size_t)(kt * 64 + key) * 6144 + kvh * 128 + d);
            int dr = idx >> 6, kc = idx & 63;
            *(bf16x8*)&Vs[dr * VSLD + kc] =
                *(const bf16x8*)(VT + (size_t)(kvh * 128 + dr) * 2048 + kt * 64 + kc);
        }
        __syncthreads();

        // S = Q K^T : 32 q rows x 64 keys per wave
        f32x4 sacc[2][4];
#pragma unroll
        for (int rs = 0; rs < 2; rs++)
#pragma unroll
            for (int ks = 0; ks < 4; ks++) sacc[rs][ks] = (f32x4){0.f, 0.f, 0.f, 0.f};
#pragma unroll
        for (int ks = 0; ks < 4; ks++)
#pragma unroll
            for (int f = 0; f < 4; f++) {
                bf16x8 bk = *(const bf16x8*)&Ks[(ks * 16 + lrow) * KSLD + f * 32 + lk8];
#pragma unroll
                for (int rs = 0; rs < 2; rs++)
                    sacc[rs][ks] = __builtin_amdgcn_mfma_f32_16x16x32_bf16(aq[rs][f], bk, sacc[rs][ks], 0, 0, 0);
            }

        // fixed-max softmax, per-lane l accumulate, P -> LDS (A-layout transit)
#pragma unroll
        for (int rs = 0; rs < 2; rs++)
#pragma unroll
            for (int ks = 0; ks < 4; ks++) {
                int keyg = kt * 64 + ks * 16 + lrow;
#pragma unroll
                for (int r = 0; r < 4; r++) {
                    int qg = q0 + rs * 16 + quad * 4 + r;
                    float p = (keyg > qg) ? 0.f : __expf(sacc[rs][ks][r] * sc);
                    l_part[rs][r] += p;
                    Pw[wave][rs][(quad * 4 + r) * PSLD + ks * 16 + lrow] = f2bf(p);
                }
            }

        // P x V^T  [no barrier: Pw wave-private]
#pragma unroll
        for (int kp = 0; kp < 2; kp++) {
            bf16x8 ap[2];
#pragma unroll
            for (int rs = 0; rs < 2; rs++)
                ap[rs] = *(const bf16x8*)&Pw[wave][rs][lrow * PSLD + kp * 32 + lk8];
#pragma unroll
            for (int dt = 0; dt < 8; dt++) {
                bf16x8 bv = *(const bf16x8*)&Vs[(dt * 16 + lrow) * VSLD + kp * 32 + lk8];
#pragma unroll
                for (int rs = 0; rs < 2; rs++)
                    o_acc[rs][dt] = __builtin_amdgcn_mfma_f32_16x16x32_bf16(ap[rs], bv, o_acc[rs][dt], 0, 0, 0);
            }
        }
    }

    // deferred l reduction (keys spread over 16 lanes) + store
#pragma unroll
    for (int rs = 0; rs < 2; rs++)
#pragma unroll
        for (int r = 0; r < 4; r++) {
            float l = l_part[rs][r];
#pragma unroll
            for (int off = 1; off < 16; off <<= 1) l += __shfl_xor(l, off, 64);
            float inv = 1.f / l;
#pragma unroll
            for (int dt = 0; dt < 8; dt++) {
                int qg = q0 + rs * 16 + quad * 4 + r;
                AO[(size_t)qg * 4096 + h * 128 + dt * 16 + lrow] =
                    f2bf(o_acc[rs][dt][r] * inv);
            }
        }
}

// ---------------------------------------------------------------------------
extern "C" void kernel_launch(void* const* d_in, const int* in_sizes, int n_in,
                              void* d_out, int out_size, void* d_ws, size_t ws_size,
                              hipStream_t stream) {
    (void)in_sizes; (void)n_in; (void)out_size; (void)ws_size;
    const float* x  = (const float*)d_in[0];
    const float* wq = (const float*)d_in[1];
    const float* wk = (const float*)d_in[2];
    const float* wv = (const float*)d_in[3];
    const float* wo = (const float*)d_in[4];
    const float* fc = (const float*)d_in[5];
    const float* fs = (const float*)d_in[6];
    float* out = (float*)d_out;

    char* ws = (char*)d_ws;
    size_t off = 0;
    auto carve = [&](size_t bytes) { char* p = ws + off; off = (off + bytes + 255) & ~(size_t)255; return p; };
    short* xb    = (short*)carve(2048u * 4096u * 2);   // x bf16; reused as AO
    short* wqkvT = (short*)carve(6144u * 4096u * 2);   // rows: 0-4095 wq^T, 4096-5119 wk^T, 5120-6143 wv^T
    short* woT   = (short*)carve(4096u * 4096u * 2);
    short* qkvb  = (short*)carve(2048u * 6144u * 2);   // cols: Q | K | V
    short* vtb   = (short*)carve(1024u * 2048u * 2);   // V^T [kvh*128+d][s]
    short* aob   = xb;

    dim3 tb(32, 8);
    cvt_f32_bf16<<<8192, 256, 0, stream>>>(x, xb, 2048 * 4096);
    transpose_f32_bf16<<<dim3(128, 64), tb, 0, stream>>>(wq, wqkvT, 4096, 4096);
    transpose_f32_bf16<<<dim3(32, 64),  tb, 0, stream>>>(wk, wqkvT + (size_t)4096 * 4096, 4096, 1024);
    transpose_f32_bf16<<<dim3(32, 64),  tb, 0, stream>>>(wv, wqkvT + (size_t)5120 * 4096, 4096, 1024);
    transpose_f32_bf16<<<dim3(128, 64), tb, 0, stream>>>(wo, woT, 4096, 4096);

    gemm_bf16<<<dim3(48, 16), 256, 0, stream>>>(xb, wqkvT, nullptr, qkvb, 2048, 6144, 4096);

    rope_kernel<<<2048, 256, 0, stream>>>(qkvb, fc, fs);
    transpose_bf16<<<dim3(32, 64), tb, 0, stream>>>(qkvb + 5120, vtb, 2048, 1024, 6144);

    attn_kernel<<<dim3(64, 8), 256, 0, stream>>>(qkvb, vtb, aob);

    gemm_bf16<<<dim3(32, 16), 256, 0, stream>>>(aob, woT, out, nullptr, 2048, 4096, 4096);
}